// Round 1
// baseline (1423.041 us; speedup 1.0000x reference)
//
#include <hip/hip_runtime.h>
#include <hip/hip_bf16.h>

#define B_ 4
#define T_ 1024
#define DM 512
#define H_ 8
#define DK 64

typedef __attribute__((ext_vector_type(4))) float f32x4;
typedef __attribute__((ext_vector_type(8))) short bf16x8;

__device__ __forceinline__ unsigned short f2bf(float f) {
  __hip_bfloat16 h = __float2bfloat16(f);
  return *reinterpret_cast<unsigned short*>(&h);
}
__device__ __forceinline__ float lo_bf(unsigned w) {
  union { unsigned u; float f; } x; x.u = w << 16; return x.f;
}
__device__ __forceinline__ float hi_bf(unsigned w) {
  union { unsigned u; float f; } x; x.u = w & 0xffff0000u; return x.f;
}

// ---------------------------------------------------------------------------
// Generic f32 tiled GEMM: C[M,N] = X[M,K] @ op(W)
//  BLAY 0: W is [N,K] row-major (NT, used for x @ w.T)
//  BLAY 1: W is [K,N] row-major (NN, used for A @ V)
//  OMODE 0: plain row-major [M,N]
//  OMODE 1: qkv split: row r=(b,t), col c=(h,d) -> out[b,h,t,d]
//  OMODE 2: ctx: batch z=(b,h), row=t, col=d -> out[b,t,h*64+d]
// All dims assumed multiples of 64 (M) / 64 (N tile) / 16 (K).
// ---------------------------------------------------------------------------
template<int BLAY, int OMODE>
__global__ __launch_bounds__(256)
void gemm64(const float* __restrict__ X, const float* __restrict__ W,
            float* __restrict__ out, int M, int N, int K,
            long xbatch, long wbatch) {
  __shared__ float Xs[16][68];
  __shared__ float Ws[16][68];
  const int t = threadIdx.x;
  const long bz = blockIdx.z;
  X += bz * xbatch;
  W += bz * wbatch;
  const int n0 = blockIdx.x * 64, m0 = blockIdx.y * 64;
  const int tx = t & 15, ty = t >> 4;
  float acc[4][4] = {};
  for (int k0 = 0; k0 < K; k0 += 16) {
    {
      int m = t >> 2, ks = (t & 3) << 2;
      float4 v = *(const float4*)&X[(long)(m0 + m) * K + k0 + ks];
      Xs[ks + 0][m] = v.x; Xs[ks + 1][m] = v.y;
      Xs[ks + 2][m] = v.z; Xs[ks + 3][m] = v.w;
    }
    if (BLAY == 0) {
      int n = t >> 2, ks = (t & 3) << 2;
      float4 v = *(const float4*)&W[(long)(n0 + n) * K + k0 + ks];
      Ws[ks + 0][n] = v.x; Ws[ks + 1][n] = v.y;
      Ws[ks + 2][n] = v.z; Ws[ks + 3][n] = v.w;
    } else {
      int r = t >> 4, cs = (t & 15) << 2;
      *(float4*)&Ws[r][cs] = *(const float4*)&W[(long)(k0 + r) * N + n0 + cs];
    }
    __syncthreads();
#pragma unroll
    for (int kk = 0; kk < 16; ++kk) {
      float a[4], b[4];
      *(float4*)a = *(const float4*)&Xs[kk][ty << 2];
      *(float4*)b = *(const float4*)&Ws[kk][tx << 2];
#pragma unroll
      for (int i = 0; i < 4; ++i)
#pragma unroll
        for (int j = 0; j < 4; ++j)
          acc[i][j] += a[i] * b[j];
    }
    __syncthreads();
  }
#pragma unroll
  for (int i = 0; i < 4; ++i) {
    int r = m0 + (ty << 2) + i;
    int c0 = n0 + (tx << 2);
    float4 v = make_float4(acc[i][0], acc[i][1], acc[i][2], acc[i][3]);
    if (OMODE == 0) {
      *(float4*)&out[(long)r * N + c0] = v;
    } else if (OMODE == 1) {
      int b = r >> 10, tt = r & 1023, h = c0 >> 6, d = c0 & 63;
      *(float4*)&out[((long)(b * H_ + h) * T_ + tt) * DK + d] = v;
    } else {
      int b = (int)bz >> 3, h = (int)bz & 7;
      *(float4*)&out[(long)(b * T_ + r) * DM + h * DK + c0] = v;
    }
  }
}

// ---------------------------------------------------------------------------
// Ma accumulation helper: 3x3 conv contribution of 8 channels from a bf16 LDS
// halo array src[8][34][36] into acc[8 outch][4 px].  aw indices are
// wave-uniform -> scalar loads.
// ---------------------------------------------------------------------------
__device__ __forceinline__ void ma_accum(const unsigned short* __restrict__ src,
                                         int ibase,
                                         const float* __restrict__ aw,
                                         int py, int px0, float acc[H_][4]) {
  for (int i = 0; i < 8; ++i) {
#pragma unroll
    for (int dy = 0; dy < 3; ++dy) {
      const unsigned* p =
          (const unsigned*)&src[((i * 34) + py + dy) * 36 + px0];
      unsigned w0 = p[0], w1 = p[1], w2 = p[2];
      float f[6] = { lo_bf(w0), hi_bf(w0), lo_bf(w1),
                     hi_bf(w1), lo_bf(w2), hi_bf(w2) };
#pragma unroll
      for (int dx = 0; dx < 3; ++dx) {
#pragma unroll
        for (int o = 0; o < 8; ++o) {
          float w = aw[((o * 16 + (ibase + i)) * 3 + dy) * 3 + dx];
#pragma unroll
          for (int pp = 0; pp < 4; ++pp)
            acc[o][pp] += w * f[dx + pp];
        }
      }
    }
  }
}

// ---------------------------------------------------------------------------
// Fused: M = QK^T (MFMA bf16), Mt = conv3(prev)+tb, Ma = conv3(cat(M,Mt))+ab,
// logits = Ma/8 written to the A region of d_out.  One 32x32 tile per block.
// Halo values of M/Mt outside the image are zero (conv2 zero-padding).
// ---------------------------------------------------------------------------
__global__ __launch_bounds__(256)
void fused_logits(const float* __restrict__ Qp, const float* __restrict__ Kp,
                  const float* __restrict__ prev,
                  const float* __restrict__ tw, const float* __restrict__ tb,
                  const float* __restrict__ aw, const float* __restrict__ ab,
                  float* __restrict__ logits) {
  __shared__ unsigned short Mh[H_][34][36];      // 19584 B  (bf16 M halo)
  __shared__ unsigned short Mt[H_][34][36];      // 19584 B  (bf16 Mt halo)
  __shared__ __align__(16) unsigned char r3[8 * 36 * 38 * 2]; // 21888 B union
  __shared__ float tw_s[576];
  __shared__ float tb_s[8];

  const int t = threadIdx.x;
  const int b = blockIdx.z, qt = blockIdx.y, kt = blockIdx.x;
  const int q0 = qt * 32, k0 = kt * 32;
  const int wave = t >> 6, lane = t & 63;
  const int lrow = lane & 15, lquad = lane >> 4;

  // stage tw/tb (lane-varying access later -> LDS)
  for (int idx = t; idx < 584; idx += 256) {
    if (idx < 576) tw_s[idx] = tw[idx];
    else tb_s[idx - 576] = tb[idx - 576];
  }

  // ---- Phase A: M halo via MFMA, one head at a time -----------------------
  unsigned short (*QKbf)[48][64] = (unsigned short (*)[48][64])r3;
  for (int h = 0; h < H_; ++h) {
    __syncthreads();  // protect QKbf reuse from previous head's MFMA reads
    for (int idx = t; idx < 2 * 48 * 64; idx += 256) {
      int arr = (idx >= 3072) ? 1 : 0;
      int rem = idx - arr * 3072;
      int row = rem >> 6, d = rem & 63;
      int srow = (arr ? k0 : q0) - 1 + row;
      float v = 0.f;
      if (srow >= 0 && srow < T_) {
        const float* P = arr ? Kp : Qp;
        v = P[((long)(b * H_ + h) * T_ + srow) * DK + d];
      }
      QKbf[arr][row][d] = f2bf(v);
    }
    __syncthreads();
    for (int job = wave; job < 9; job += 4) {
      int ti = job / 3, tj = job - ti * 3;
      f32x4 acc = {0.f, 0.f, 0.f, 0.f};
#pragma unroll
      for (int c = 0; c < 2; ++c) {
        bf16x8 av = *(const bf16x8*)&QKbf[0][ti * 16 + lrow][c * 32 + lquad * 8];
        bf16x8 bv = *(const bf16x8*)&QKbf[1][tj * 16 + lrow][c * 32 + lquad * 8];
        acc = __builtin_amdgcn_mfma_f32_16x16x32_bf16(av, bv, acc, 0, 0, 0);
      }
#pragma unroll
      for (int r = 0; r < 4; ++r) {
        int row = ti * 16 + lquad * 4 + r, col = tj * 16 + lrow;
        if (row < 34 && col < 34) Mh[h][row][col] = f2bf(acc[r]);
      }
    }
  }
  __syncthreads();

  // ---- Phase B0: stage prev halo (36x36 per channel, zero-padded) ---------
  unsigned short (*Ph)[36][38] = (unsigned short (*)[36][38])r3;
  for (int idx = t; idx < 8 * 36 * 36; idx += 256) {
    int ch = idx / 1296, rem = idx - ch * 1296;
    int row = rem / 36, col = rem - row * 36;
    int gy = q0 - 2 + row, gx = k0 - 2 + col;
    float v = 0.f;
    if (gy >= 0 && gy < T_ && gx >= 0 && gx < T_)
      v = prev[((long)(b * H_ + ch) * T_ + gy) * T_ + gx];
    Ph[ch][row][col] = f2bf(v);
  }
  __syncthreads();

  // ---- Phase B1: Mt halo, groups of 4 consecutive x -----------------------
  for (int idx = t; idx < 8 * 34 * 9; idx += 256) {
    int m = idx / 306, rem = idx - m * 306;
    int y = rem / 9, xg = rem - y * 9;
    int x0 = xg * 4;
    float av[4];
    float tbv = tb_s[m];
    av[0] = tbv; av[1] = tbv; av[2] = tbv; av[3] = tbv;
#pragma unroll
    for (int i = 0; i < 8; ++i) {
#pragma unroll
      for (int dy = 0; dy < 3; ++dy) {
        const unsigned* p = (const unsigned*)&Ph[i][y + dy][x0];
        unsigned w0 = p[0], w1 = p[1], w2 = p[2];
        float f[6] = { lo_bf(w0), hi_bf(w0), lo_bf(w1),
                       hi_bf(w1), lo_bf(w2), hi_bf(w2) };
#pragma unroll
        for (int dx = 0; dx < 3; ++dx) {
          float w = tw_s[(m * 8 + i) * 9 + dy * 3 + dx];
#pragma unroll
          for (int pp = 0; pp < 4; ++pp)
            av[pp] += w * f[dx + pp];
        }
      }
    }
    int gy = q0 - 1 + y;
    bool yok = (gy >= 0 && gy < T_);
#pragma unroll
    for (int pp = 0; pp < 4; ++pp) {
      int x = x0 + pp;
      if (x < 34) {
        int gx = k0 - 1 + x;
        float v = (yok && gx >= 0 && gx < T_) ? av[pp] : 0.f;
        Mt[m][y][x] = f2bf(v);
      }
    }
  }
  __syncthreads();

  // ---- Phase B2: Ma = conv3(cat(M,Mt)) + ab, scaled, stored ---------------
  const int py = t >> 3;
  const int px0 = (t & 7) << 2;
  float acc[H_][4] = {};
  ma_accum(&Mh[0][0][0], 0, aw, py, px0, acc);
  ma_accum(&Mt[0][0][0], 8, aw, py, px0, acc);

#pragma unroll
  for (int o = 0; o < 8; ++o) {
    float abv = ab[o];
    float4 v;
    v.x = (acc[o][0] + abv) * 0.125f;
    v.y = (acc[o][1] + abv) * 0.125f;
    v.z = (acc[o][2] + abv) * 0.125f;
    v.w = (acc[o][3] + abv) * 0.125f;
    *(float4*)&logits[((long)(b * H_ + o) * T_ + (q0 + py)) * T_ + k0 + px0] = v;
  }
}

// ---------------------------------------------------------------------------
// In-place masked softmax over the last dim (one row of 1024 per block).
// ---------------------------------------------------------------------------
__global__ __launch_bounds__(256)
void softmax_rows(float* __restrict__ A, const int* __restrict__ mask) {
  const int t = threadIdx.x;
  const int q = blockIdx.x, h = blockIdx.y, b = blockIdx.z;
  float* row = A + ((long)(b * H_ + h) * T_ + q) * T_;
  float4 v = *(float4*)&row[t * 4];
  int4 mv = *(const int4*)&mask[b * T_ + t * 4];
  v.x = (mv.x == 0) ? -1e9f : v.x;
  v.y = (mv.y == 0) ? -1e9f : v.y;
  v.z = (mv.z == 0) ? -1e9f : v.z;
  v.w = (mv.w == 0) ? -1e9f : v.w;

  __shared__ float r1[4], r2[4];
  const int wave = t >> 6, lane = t & 63;

  float mx4 = fmaxf(fmaxf(v.x, v.y), fmaxf(v.z, v.w));
  for (int o = 32; o > 0; o >>= 1) mx4 = fmaxf(mx4, __shfl_xor(mx4, o, 64));
  if (lane == 0) r1[wave] = mx4;
  __syncthreads();
  float mx = fmaxf(fmaxf(r1[0], r1[1]), fmaxf(r1[2], r1[3]));

  float e0 = __expf(v.x - mx), e1 = __expf(v.y - mx);
  float e2 = __expf(v.z - mx), e3 = __expf(v.w - mx);
  float s4 = (e0 + e1) + (e2 + e3);
  for (int o = 32; o > 0; o >>= 1) s4 += __shfl_xor(s4, o, 64);
  if (lane == 0) r2[wave] = s4;
  __syncthreads();
  float inv = 1.0f / (r2[0] + r2[1] + r2[2] + r2[3]);

  float4 ov;
  ov.x = e0 * inv; ov.y = e1 * inv; ov.z = e2 * inv; ov.w = e3 * inv;
  *(float4*)&row[t * 4] = ov;
}

// ---------------------------------------------------------------------------
extern "C" void kernel_launch(void* const* d_in, const int* in_sizes, int n_in,
                              void* d_out, int out_size, void* d_ws,
                              size_t ws_size, hipStream_t stream) {
  const float* q    = (const float*)d_in[0];
  const float* k    = (const float*)d_in[1];
  const float* v    = (const float*)d_in[2];
  const int*   mask = (const int*)  d_in[3];
  const float* prev = (const float*)d_in[4];
  const float* w_q  = (const float*)d_in[5];
  const float* w_k  = (const float*)d_in[6];
  const float* w_v  = (const float*)d_in[7];
  const float* w_o  = (const float*)d_in[8];
  const float* tw   = (const float*)d_in[9];
  const float* tb   = (const float*)d_in[10];
  const float* aw   = (const float*)d_in[11];
  const float* ab   = (const float*)d_in[12];

  float* out  = (float*)d_out;
  float* Aout = out + (long)B_ * T_ * DM;   // A region: (4,8,1024,1024)

  float* ws  = (float*)d_ws;                // 32 MiB used
  float* Qp  = ws;
  float* Kp  = Qp + (long)B_ * H_ * T_ * DK;
  float* Vp  = Kp + (long)B_ * H_ * T_ * DK;
  float* ctx = Vp + (long)B_ * H_ * T_ * DK;

  dim3 blk(256);

  // Q/K/V projections: (4096x512) @ W^T, head-split output
  gemm64<0, 1><<<dim3(8, 64, 1), blk, 0, stream>>>(q, w_q, Qp, 4096, 512, 512, 0, 0);
  gemm64<0, 1><<<dim3(8, 64, 1), blk, 0, stream>>>(k, w_k, Kp, 4096, 512, 512, 0, 0);
  gemm64<0, 1><<<dim3(8, 64, 1), blk, 0, stream>>>(v, w_v, Vp, 4096, 512, 512, 0, 0);

  // fused M + convs -> logits (into A region)
  fused_logits<<<dim3(32, 32, 4), blk, 0, stream>>>(Qp, Kp, prev, tw, tb, aw, ab, Aout);

  // softmax in place on A region
  softmax_rows<<<dim3(1024, 8, 4), blk, 0, stream>>>(Aout, mask);

  // ctx = A @ V   (batched over (b,h)), output interleaved (b,t,h*64+d)
  gemm64<1, 2><<<dim3(1, 16, 32), blk, 0, stream>>>(Aout, Vp, ctx, 1024, 64, 1024,
                                                    (long)T_ * T_, (long)T_ * DK);

  // final projection: ctx @ w_o^T -> out
  gemm64<0, 0><<<dim3(8, 64, 1), blk, 0, stream>>>(ctx, w_o, out, 4096, 512, 512, 0, 0);
}

// Round 2
// 759.292 us; speedup vs baseline: 1.8742x; 1.8742x over previous
//
#include <hip/hip_runtime.h>
#include <hip/hip_bf16.h>

#define B_ 4
#define T_ 1024
#define DM 512
#define H_ 8
#define DK 64

typedef __attribute__((ext_vector_type(4))) float f32x4;
typedef __attribute__((ext_vector_type(8))) short bf16x8;

__device__ __forceinline__ unsigned short f2bf(float f) {
  __hip_bfloat16 h = __float2bfloat16(f);
  return *reinterpret_cast<unsigned short*>(&h);
}

// ---------------------------------------------------------------------------
// Generic f32 tiled GEMM: C[M,N] = X[M,K] @ op(W)
//  BLAY 0: W is [N,K] row-major (NT, x @ w.T) ; BLAY 1: W is [K,N] (NN, A @ V)
//  OMODE 0: row-major [M,N]
//  OMODE 1: qkv split: row r=(b,t), col c=(h,d) -> out[b,h,t,d]
//  OMODE 2: ctx: batch z=(b,h), row=t, col=d -> out[b,t,h*64+d]
//  OUTBF 1: output bf16 (only OMODE 1 uses it)
// ---------------------------------------------------------------------------
template<int BLAY, int OMODE, int OUTBF>
__global__ __launch_bounds__(256)
void gemm64(const float* __restrict__ X, const float* __restrict__ W,
            void* __restrict__ outv, int M, int N, int K,
            long xbatch, long wbatch) {
  float* out = (float*)outv;
  unsigned short* outb = (unsigned short*)outv;
  __shared__ float Xs[16][68];
  __shared__ float Ws[16][68];
  const int t = threadIdx.x;
  const long bz = blockIdx.z;
  X += bz * xbatch;
  W += bz * wbatch;
  const int n0 = blockIdx.x * 64, m0 = blockIdx.y * 64;
  const int tx = t & 15, ty = t >> 4;
  float acc[4][4] = {};
  for (int k0 = 0; k0 < K; k0 += 16) {
    {
      int m = t >> 2, ks = (t & 3) << 2;
      float4 v = *(const float4*)&X[(long)(m0 + m) * K + k0 + ks];
      Xs[ks + 0][m] = v.x; Xs[ks + 1][m] = v.y;
      Xs[ks + 2][m] = v.z; Xs[ks + 3][m] = v.w;
    }
    if (BLAY == 0) {
      int n = t >> 2, ks = (t & 3) << 2;
      float4 v = *(const float4*)&W[(long)(n0 + n) * K + k0 + ks];
      Ws[ks + 0][n] = v.x; Ws[ks + 1][n] = v.y;
      Ws[ks + 2][n] = v.z; Ws[ks + 3][n] = v.w;
    } else {
      int r = t >> 4, cs = (t & 15) << 2;
      *(float4*)&Ws[r][cs] = *(const float4*)&W[(long)(k0 + r) * N + n0 + cs];
    }
    __syncthreads();
#pragma unroll
    for (int kk = 0; kk < 16; ++kk) {
      float a[4], b[4];
      *(float4*)a = *(const float4*)&Xs[kk][ty << 2];
      *(float4*)b = *(const float4*)&Ws[kk][tx << 2];
#pragma unroll
      for (int i = 0; i < 4; ++i)
#pragma unroll
        for (int j = 0; j < 4; ++j)
          acc[i][j] += a[i] * b[j];
    }
    __syncthreads();
  }
#pragma unroll
  for (int i = 0; i < 4; ++i) {
    int r = m0 + (ty << 2) + i;
    int c0 = n0 + (tx << 2);
    float4 v = make_float4(acc[i][0], acc[i][1], acc[i][2], acc[i][3]);
    if (OMODE == 0) {
      *(float4*)&out[(long)r * N + c0] = v;
    } else if (OMODE == 1) {
      int b = r >> 10, tt = r & 1023, h = c0 >> 6, d = c0 & 63;
      long off = ((long)(b * H_ + h) * T_ + tt) * DK + d;
      if (OUTBF) {
        uint2 pk;
        pk.x = (unsigned)f2bf(v.x) | ((unsigned)f2bf(v.y) << 16);
        pk.y = (unsigned)f2bf(v.z) | ((unsigned)f2bf(v.w) << 16);
        *(uint2*)&outb[off] = pk;
      } else {
        *(float4*)&out[off] = v;
      }
    } else {
      int b = (int)bz >> 3, h = (int)bz & 7;
      *(float4*)&out[(long)(b * T_ + r) * DM + h * DK + c0] = v;
    }
  }
}

// ---------------------------------------------------------------------------
// Fused logits, MFMA everywhere.
//   Phase A : M = QK^T per head (mfma 16x16x32 bf16), 34x34 halo -> C[y][x][h]
//   Phase B0: stage prev halo channel-last -> P[36*36][8] bf16
//   Phase B1: Mt = conv3(prev)+tb as GEMM (K=8ch*9tap=72 pad 96) -> C[y][x][8+o]
//             (zero outside the image: conv2's zero padding)
//   Phase B2: Ma = conv3(cat(M,Mt))+ab as GEMM (K=16ch*9tap=144 pad 160),
//             logits = Ma/8 stored to the A region of d_out.
// Channel-last LDS layout makes every MFMA A-fragment one ds_read_b128
// (8 consecutive channels at one tap). Weight B-fragments live in registers.
// k ordering: tap-major, channel-minor -> each 8-wide j-group = one tap.
// ---------------------------------------------------------------------------
__global__ __launch_bounds__(256)
void fused_logits(const unsigned short* __restrict__ Qp,
                  const unsigned short* __restrict__ Kp,
                  const float* __restrict__ prev,
                  const float* __restrict__ tw, const float* __restrict__ tb,
                  const float* __restrict__ aw, const float* __restrict__ ab,
                  float* __restrict__ logits) {
  __shared__ __align__(16) unsigned short C[34 * 34 * 16];  // 36992 B
  __shared__ __align__(16) unsigned char U[20736];          // QK[2][48][72] | P[1296][8]
  unsigned short (*QK)[48][72] = (unsigned short (*)[48][72])U;
  unsigned short* P = (unsigned short*)U;

  const int t = threadIdx.x;
  const int b = blockIdx.z, q0 = blockIdx.y * 32, k0 = blockIdx.x * 32;
  const int wave = t >> 6, lane = t & 63;
  const int lrow = lane & 15, quad = lane >> 4;
  const int o = lrow;              // out-channel for B fragments / D columns
  const int i0 = (quad & 1) * 8;   // conv2 channel-half per quad

  // ---- per-lane weight B-fragments (registers) ---------------------------
  bf16x8 W2f[5], W1f[3];
#pragma unroll
  for (int ks = 0; ks < 5; ++ks) {
    int kk0 = ks * 32 + quad * 8;           // tap = kk0>>4, i = (kk0&15)+j
    bf16x8 f = {0, 0, 0, 0, 0, 0, 0, 0};
    if (o < 8 && kk0 < 144) {
      int tap = kk0 >> 4, ib = kk0 & 15;
#pragma unroll
      for (int j = 0; j < 8; ++j)
        f[j] = (short)f2bf(aw[o * 144 + (ib + j) * 9 + tap]);
    }
    W2f[ks] = f;
  }
#pragma unroll
  for (int ks = 0; ks < 3; ++ks) {
    int kk0 = ks * 32 + quad * 8;           // tap = kk0>>3, i = j
    bf16x8 f = {0, 0, 0, 0, 0, 0, 0, 0};
    if (o < 8 && kk0 < 72) {
      int tap = kk0 >> 3;
#pragma unroll
      for (int j = 0; j < 8; ++j)
        f[j] = (short)f2bf(tw[o * 72 + j * 9 + tap]);
    }
    W1f[ks] = f;
  }
  const float tb_r = (o < 8) ? tb[o] : 0.f;
  const float ab_r = (o < 8) ? ab[o] : 0.f;

  // ---- Phase A: M halo per head ------------------------------------------
  for (int h = 0; h < 8; ++h) {
    __syncthreads();                       // QK reuse across heads
    for (int c = t; c < 768; c += 256) {   // 2 arrays * 48 rows * 8 segs
      int arr = c >> 9 >> 0 ? 0 : 0;       // (placeholder, computed below)
      arr = (c >= 384) ? 1 : 0;
      int rem = c - arr * 384;
      int row = rem >> 3, seg = rem & 7;
      int srow = (arr ? k0 : q0) - 1 + row;
      bf16x8 v = {0, 0, 0, 0, 0, 0, 0, 0};
      if (srow >= 0 && srow < T_) {
        const unsigned short* src =
            (arr ? Kp : Qp) + ((long)((b * H_ + h) * T_ + srow)) * DK + seg * 8;
        v = *(const bf16x8*)src;
      }
      *(bf16x8*)&QK[arr][row][seg * 8] = v;
    }
    __syncthreads();
    for (int job = wave; job < 9; job += 4) {
      int ti = job / 3, tj = job - ti * 3;
      f32x4 acc = {0.f, 0.f, 0.f, 0.f};
#pragma unroll
      for (int c = 0; c < 2; ++c) {
        bf16x8 av = *(const bf16x8*)&QK[0][ti * 16 + lrow][c * 32 + quad * 8];
        bf16x8 bv = *(const bf16x8*)&QK[1][tj * 16 + lrow][c * 32 + quad * 8];
        acc = __builtin_amdgcn_mfma_f32_16x16x32_bf16(av, bv, acc, 0, 0, 0);
      }
#pragma unroll
      for (int r = 0; r < 4; ++r) {
        int row = ti * 16 + quad * 4 + r, col = tj * 16 + lrow;
        if (row < 34 && col < 34)
          C[(row * 34 + col) * 16 + h] = f2bf(acc[r]);
      }
    }
  }
  __syncthreads();

  // ---- Phase B0: prev halo, channel-last ---------------------------------
  for (int p = t; p < 1296; p += 256) {    // 36*36 pixels
    int row = p / 36, col = p - row * 36;
    int gy = q0 - 2 + row, gx = k0 - 2 + col;
    bf16x8 v = {0, 0, 0, 0, 0, 0, 0, 0};
    if (gy >= 0 && gy < T_ && gx >= 0 && gx < T_) {
      const float* src = prev + ((long)(b * H_) * T_ + gy) * T_ + gx;
#pragma unroll
      for (int ch = 0; ch < 8; ++ch)
        v[ch] = (short)f2bf(src[(long)ch * T_ * T_]);
    }
    *(bf16x8*)&P[p * 8] = v;               // contiguous b128, conflict-free
  }
  __syncthreads();

  // ---- Phase B1: Mt = conv1(prev)+tb -> C channels 8..15 ------------------
  for (int mt = wave; mt < 73; mt += 4) {  // 1156 px in 73 m-tiles of 16
    int pin = mt * 16 + lrow;
    if (pin > 1155) pin = 1155;            // pad pixels: valid addr, discarded
    int yi = pin / 34, xi = pin - yi * 34;
    f32x4 acc = {0.f, 0.f, 0.f, 0.f};
#pragma unroll
    for (int ks = 0; ks < 3; ++ks) {
      int tap = ks * 4 + quad;             // kk0>>3
      if (tap > 8) tap = 8;                // pad k: B frag is 0
      int dy = tap / 3, dx = tap - dy * 3;
      bf16x8 av = *(const bf16x8*)&P[((yi + dy) * 36 + xi + dx) * 8];
      acc = __builtin_amdgcn_mfma_f32_16x16x32_bf16(av, W1f[ks], acc, 0, 0, 0);
    }
#pragma unroll
    for (int r = 0; r < 4; ++r) {
      int po = mt * 16 + quad * 4 + r;
      if (o < 8 && po < 1156) {
        int yo = po / 34, xo = po - yo * 34;
        int gy = q0 - 1 + yo, gx = k0 - 1 + xo;
        float val = (gy >= 0 && gy < T_ && gx >= 0 && gx < T_) ? acc[r] + tb_r
                                                               : 0.f;
        C[po * 16 + 8 + o] = f2bf(val);
      }
    }
  }
  __syncthreads();

  // ---- Phase B2: logits = (conv2(cat)+ab)/8 -> A region -------------------
  for (int mt = wave; mt < 64; mt += 4) {  // 1024 px in 64 m-tiles
    int pin = mt * 16 + lrow;
    int yi = pin >> 5, xi = pin & 31;
    f32x4 acc = {0.f, 0.f, 0.f, 0.f};
#pragma unroll
    for (int ks = 0; ks < 5; ++ks) {
      int tap = ks * 2 + (quad >> 1);      // kk0>>4
      if (tap > 8) tap = 8;                // pad k: B frag is 0
      int dy = tap / 3, dx = tap - dy * 3;
      bf16x8 av = *(const bf16x8*)&C[((yi + dy) * 34 + xi + dx) * 16 + i0];
      acc = __builtin_amdgcn_mfma_f32_16x16x32_bf16(av, W2f[ks], acc, 0, 0, 0);
    }
#pragma unroll
    for (int r = 0; r < 4; ++r) {
      int po = mt * 16 + quad * 4 + r;
      if (o < 8) {
        int yo = po >> 5, xo = po & 31;
        logits[((long)(b * H_ + o) * T_ + q0 + yo) * T_ + k0 + xo] =
            (acc[r] + ab_r) * 0.125f;
      }
    }
  }
}

// ---------------------------------------------------------------------------
// In-place masked softmax over the last dim (one row of 1024 per block).
// ---------------------------------------------------------------------------
__global__ __launch_bounds__(256)
void softmax_rows(float* __restrict__ A, const int* __restrict__ mask) {
  const int t = threadIdx.x;
  const int q = blockIdx.x, h = blockIdx.y, b = blockIdx.z;
  float* row = A + ((long)(b * H_ + h) * T_ + q) * T_;
  float4 v = *(float4*)&row[t * 4];
  int4 mv = *(const int4*)&mask[b * T_ + t * 4];
  v.x = (mv.x == 0) ? -1e9f : v.x;
  v.y = (mv.y == 0) ? -1e9f : v.y;
  v.z = (mv.z == 0) ? -1e9f : v.z;
  v.w = (mv.w == 0) ? -1e9f : v.w;

  __shared__ float r1[4], r2[4];
  const int wave = t >> 6, lane = t & 63;

  float mx4 = fmaxf(fmaxf(v.x, v.y), fmaxf(v.z, v.w));
  for (int of = 32; of > 0; of >>= 1) mx4 = fmaxf(mx4, __shfl_xor(mx4, of, 64));
  if (lane == 0) r1[wave] = mx4;
  __syncthreads();
  float mx = fmaxf(fmaxf(r1[0], r1[1]), fmaxf(r1[2], r1[3]));

  float e0 = __expf(v.x - mx), e1 = __expf(v.y - mx);
  float e2 = __expf(v.z - mx), e3 = __expf(v.w - mx);
  float s4 = (e0 + e1) + (e2 + e3);
  for (int of = 32; of > 0; of >>= 1) s4 += __shfl_xor(s4, of, 64);
  if (lane == 0) r2[wave] = s4;
  __syncthreads();
  float inv = 1.0f / (r2[0] + r2[1] + r2[2] + r2[3]);

  float4 ov;
  ov.x = e0 * inv; ov.y = e1 * inv; ov.z = e2 * inv; ov.w = e3 * inv;
  *(float4*)&row[t * 4] = ov;
}

// ---------------------------------------------------------------------------
extern "C" void kernel_launch(void* const* d_in, const int* in_sizes, int n_in,
                              void* d_out, int out_size, void* d_ws,
                              size_t ws_size, hipStream_t stream) {
  const float* q    = (const float*)d_in[0];
  const float* k    = (const float*)d_in[1];
  const float* v    = (const float*)d_in[2];
  const int*   mask = (const int*)  d_in[3];
  const float* prev = (const float*)d_in[4];
  const float* w_q  = (const float*)d_in[5];
  const float* w_k  = (const float*)d_in[6];
  const float* w_v  = (const float*)d_in[7];
  const float* w_o  = (const float*)d_in[8];
  const float* tw   = (const float*)d_in[9];
  const float* tb   = (const float*)d_in[10];
  const float* aw   = (const float*)d_in[11];
  const float* ab   = (const float*)d_in[12];

  float* out  = (float*)d_out;
  float* Aout = out + (long)B_ * T_ * DM;   // A region: (4,8,1024,1024) f32

  char* wsb = (char*)d_ws;                   // 24 MiB used
  unsigned short* Qp = (unsigned short*)wsb;                     // 4 MB bf16
  unsigned short* Kp = (unsigned short*)(wsb + (4L << 20));      // 4 MB bf16
  float* Vp  = (float*)(wsb + (8L << 20));                       // 8 MB f32
  float* ctx = (float*)(wsb + (16L << 20));                      // 8 MB f32

  dim3 blk(256);

  // Q/K projections -> bf16 head-split; V -> f32 head-split
  gemm64<0, 1, 1><<<dim3(8, 64, 1), blk, 0, stream>>>(q, w_q, Qp, 4096, 512, 512, 0, 0);
  gemm64<0, 1, 1><<<dim3(8, 64, 1), blk, 0, stream>>>(k, w_k, Kp, 4096, 512, 512, 0, 0);
  gemm64<0, 1, 0><<<dim3(8, 64, 1), blk, 0, stream>>>(v, w_v, Vp, 4096, 512, 512, 0, 0);

  // fused M + convs -> logits (into A region), all-MFMA
  fused_logits<<<dim3(32, 32, 4), blk, 0, stream>>>(Qp, Kp, prev, tw, tb, aw, ab, Aout);

  // softmax in place on A region
  softmax_rows<<<dim3(1024, 8, 4), blk, 0, stream>>>(Aout, mask);

  // ctx = A @ V (batched over (b,h)), output interleaved (b,t,h*64+d)
  gemm64<1, 2, 0><<<dim3(1, 16, 32), blk, 0, stream>>>(Aout, Vp, ctx, 1024, 64, 1024,
                                                       (long)T_ * T_, (long)T_ * DK);

  // final projection: ctx @ w_o^T -> out
  gemm64<0, 0, 0><<<dim3(8, 64, 1), blk, 0, stream>>>(ctx, w_o, out, 4096, 512, 512, 0, 0);
}